// Round 3
// baseline (192.441 us; speedup 1.0000x reference)
//
#include <hip/hip_runtime.h>

#define N_SAMPLES 8192
#define BLOCK 256
#define VEC 4
#define ITERS (N_SAMPLES / (BLOCK * VEC))   // 8 float4 loads per thread

typedef float f32x4 __attribute__((ext_vector_type(4)));

__global__ __launch_bounds__(BLOCK) void noise_layer_kernel(
    const float* __restrict__ pub_sign,   // (batch,)
    const float* __restrict__ priv_sign,  // (batch, n_samples)
    const float* __restrict__ param_b,    // (1,1)
    const float* __restrict__ param_c,    // (1,1)
    float* __restrict__ out)              // (batch,)
{
    const int b = blockIdx.x;
    const float B = param_b[0];
    const float C = param_c[0];

    // y = 2*sigmoid(s) - 1 = 1 - 2/(1 + e^s); accumulate r = 1/(1 + e^s),
    // then mean = 1 - (2/N)*sum(r).  Work in base-2: e^s = 2^(s*log2e).
    const float L2E   = 1.44269504088896340736f;
    const float CL    = C * L2E;
    const float baseL = pub_sign[b] * B * L2E;
    const float LIM   = 20.0f * L2E;          // clamp(s,±20) == clamp(s*L2E, ±20*L2E)

    const f32x4* row = reinterpret_cast<const f32x4*>(
        priv_sign + (size_t)b * N_SAMPLES);

    // Hoist all loads: 8 x 16B in flight per thread (plain loads -> LLC can serve).
    f32x4 v[ITERS];
#pragma unroll
    for (int i = 0; i < ITERS; ++i)
        v[i] = row[threadIdx.x + i * BLOCK];

    float r_sum = 0.0f;
#pragma unroll
    for (int i = 0; i < ITERS; ++i) {
#pragma unroll
        for (int j = 0; j < 4; ++j) {
            float s2 = fmaf(v[i][j], CL, baseL);      // v_fma_f32
            s2 = fminf(LIM, fmaxf(-LIM, s2));         // v_med3_f32
            float e = exp2f(s2);                      // v_exp_f32
            r_sum += __builtin_amdgcn_rcpf(1.0f + e); // v_add + v_rcp + v_add
        }
    }

    // wave (64-lane) shuffle reduction
#pragma unroll
    for (int off = 32; off > 0; off >>= 1)
        r_sum += __shfl_down(r_sum, off, 64);

    __shared__ float part[BLOCK / 64];
    const int wave = threadIdx.x >> 6;
    const int lane = threadIdx.x & 63;
    if (lane == 0) part[wave] = r_sum;
    __syncthreads();

    if (threadIdx.x == 0) {
        float t = 0.0f;
#pragma unroll
        for (int w = 0; w < BLOCK / 64; ++w) t += part[w];
        // mean = 1 - 2*t/N = 1 - t/4096
        out[b] = 1.0f - t * (1.0f / (float)(N_SAMPLES / 2));
    }
}

extern "C" void kernel_launch(void* const* d_in, const int* in_sizes, int n_in,
                              void* d_out, int out_size, void* d_ws, size_t ws_size,
                              hipStream_t stream) {
    const float* pub_sign  = (const float*)d_in[0];   // (4096,)
    const float* priv_sign = (const float*)d_in[1];   // (4096, 8192, 1)
    const float* param_b   = (const float*)d_in[2];   // (1,1)
    const float* param_c   = (const float*)d_in[3];   // (1,1)
    float* out = (float*)d_out;                       // (4096, 1, 1)

    const int batch = in_sizes[0];                    // 4096
    noise_layer_kernel<<<batch, BLOCK, 0, stream>>>(
        pub_sign, priv_sign, param_b, param_c, out);
}

// Round 4
// 183.940 us; speedup vs baseline: 1.0462x; 1.0462x over previous
//
#include <hip/hip_runtime.h>

#define N_SAMPLES 8192
#define BLOCK 256
#define VEC 4
#define ITERS (N_SAMPLES / (BLOCK * VEC))   // 8 float4 loads per thread

typedef float f32x4 __attribute__((ext_vector_type(4)));

__global__ __launch_bounds__(BLOCK) void noise_layer_kernel(
    const float* __restrict__ pub_sign,   // (batch,)
    const float* __restrict__ priv_sign,  // (batch, n_samples)
    const float* __restrict__ param_b,    // (1,1)
    const float* __restrict__ param_c,    // (1,1)
    float* __restrict__ out)              // (batch,)
{
    const int b = blockIdx.x;

    // y = 2*sigmoid(s) - 1 = 1 - 2/(1+e^s); accumulate r = 1/(1+e^s),
    // mean = 1 - (2/N)*sum(r).  Base-2: e^s = 2^(s*log2e).
    // Pairwise: 1/(1+e0) + 1/(1+e1) = (2+e0+e1) / ((1+e0)(1+e1))  -> 1 rcp / 2 elems.
    // Clamp is REQUIRED for safety: unclamped s2 can reach ~±140 -> exp2 = inf
    // -> inf*0 = NaN in the pair fold. Clamped: e <= 2^28.85, den <= 2^58, finite.
    const float L2E   = 1.44269504088896340736f;
    const float CL    = param_c[0] * L2E;
    const float baseL = pub_sign[b] * param_b[0] * L2E;
    const float LIM   = 20.0f * L2E;

    const f32x4* row = reinterpret_cast<const f32x4*>(
        priv_sign + (size_t)b * N_SAMPLES);

    const f32x4 CL4   = {CL, CL, CL, CL};
    const f32x4 base4 = {baseL, baseL, baseL, baseL};
    const f32x4 lim4  = {LIM, LIM, LIM, LIM};
    const f32x4 nlim4 = {-LIM, -LIM, -LIM, -LIM};

    float r_sum = 0.0f;
#pragma unroll
    for (int i = 0; i < ITERS; ++i) {
        f32x4 v = __builtin_nontemporal_load(&row[threadIdx.x + i * BLOCK]);
        // vector form -> v_pk_fma_f32 / packed min-max where available
        f32x4 s = v * CL4 + base4;
        s = __builtin_elementwise_min(lim4, __builtin_elementwise_max(nlim4, s));

        float e0 = exp2f(s[0]);
        float e1 = exp2f(s[1]);
        float e2 = exp2f(s[2]);
        float e3 = exp2f(s[3]);

        float t01 = e0 + e1;
        float t23 = e2 + e3;
        float d01 = fmaf(e0, e1, 1.0f + t01);
        float d23 = fmaf(e2, e3, 1.0f + t23);
        r_sum += (2.0f + t01) * __builtin_amdgcn_rcpf(d01);
        r_sum += (2.0f + t23) * __builtin_amdgcn_rcpf(d23);
    }

    // wave (64-lane) shuffle reduction
#pragma unroll
    for (int off = 32; off > 0; off >>= 1)
        r_sum += __shfl_down(r_sum, off, 64);

    __shared__ float part[BLOCK / 64];
    const int wave = threadIdx.x >> 6;
    const int lane = threadIdx.x & 63;
    if (lane == 0) part[wave] = r_sum;
    __syncthreads();

    if (threadIdx.x == 0) {
        float t = 0.0f;
#pragma unroll
        for (int w = 0; w < BLOCK / 64; ++w) t += part[w];
        // mean = 1 - 2*t/N
        out[b] = 1.0f - t * (1.0f / (float)(N_SAMPLES / 2));
    }
}

extern "C" void kernel_launch(void* const* d_in, const int* in_sizes, int n_in,
                              void* d_out, int out_size, void* d_ws, size_t ws_size,
                              hipStream_t stream) {
    const float* pub_sign  = (const float*)d_in[0];   // (4096,)
    const float* priv_sign = (const float*)d_in[1];   // (4096, 8192, 1)
    const float* param_b   = (const float*)d_in[2];   // (1,1)
    const float* param_c   = (const float*)d_in[3];   // (1,1)
    float* out = (float*)d_out;                       // (4096, 1, 1)

    const int batch = in_sizes[0];                    // 4096
    noise_layer_kernel<<<batch, BLOCK, 0, stream>>>(
        pub_sign, priv_sign, param_b, param_c, out);
}